// Round 1
// baseline (723.092 us; speedup 1.0000x reference)
//
#include <hip/hip_runtime.h>
#include <hip/hip_bf16.h>

typedef __hip_bfloat16 bf16;
typedef __attribute__((ext_vector_type(8))) short short8;
typedef __attribute__((ext_vector_type(4))) float f32x4;

__device__ __forceinline__ float b2f(unsigned short u) {
  union { unsigned u; float f; } x; x.u = ((unsigned)u) << 16; return x.f;
}
__device__ __forceinline__ bf16 f2b(float f) { return __float2bfloat16(f); }

#define BM 128
#define BN 128
#define BK 32

#define GLOAD_LDS16(gp, lp) __builtin_amdgcn_global_load_lds( \
    (const __attribute__((address_space(1))) void*)(gp), \
    (__attribute__((address_space(3))) void*)(lp), 16, 0, 0)

// ---------------- prep: bf16 weight layouts ----------------
// W2bf[n][k]  = W2[n][k]        (B for K2: B[k][n]=W2[n][k] = W2^T)
// W2Tbf[n][k] = W2[k][n]        (B for K3: B[k][n]=W2[k][n])
// Wf2bf[n][k] = Wf2[n][k]       (B for K4b)
// Wc[i][j<16] = W1[i][j] ; Wc[i][16+j] = Wff[j][i]   (for K6)
__global__ __launch_bounds__(256) void prep(
    const float* __restrict__ W2, const float* __restrict__ Wf2,
    const float* __restrict__ W1, const float* __restrict__ Wff,
    bf16* __restrict__ W2bf, bf16* __restrict__ W2Tbf,
    bf16* __restrict__ Wf2bf, bf16* __restrict__ Wc)
{
  int i = blockIdx.x * 256 + threadIdx.x;
  int r = i >> 10, c = i & 1023;
  W2bf[i]  = f2b(W2[i]);
  W2Tbf[i] = f2b(W2[c * 1024 + r]);
  Wf2bf[i] = f2b(Wf2[i]);
  if (i < 1024 * 32) {
    int ii = i >> 5, jp = i & 31;
    Wc[i] = f2b(jp < 16 ? W1[ii * 16 + jp] : Wff[(jp - 16) * 1024 + ii]);
  }
}

// ---------------- K1: h1 = tanh(z @ W1^T + b1) ----------------
__global__ __launch_bounds__(256) void k1(
    const float* __restrict__ z, const float* __restrict__ W1,
    const float* __restrict__ b1, bf16* __restrict__ h1, long grow0)
{
  __shared__ float zs[32][16];
  const int tid = threadIdx.x;
  const long r0 = (long)blockIdx.x * 32;
  for (int i = tid; i < 512; i += 256) {
    int r = i >> 4, c = i & 15;
    zs[r][c] = z[(grow0 + r0 + r) * 16 + c];
  }
  __syncthreads();
  #pragma unroll
  for (int jj = 0; jj < 4; ++jj) {
    const int c = tid + jj * 256;
    float w[16];
    #pragma unroll
    for (int k = 0; k < 16; ++k) w[k] = W1[c * 16 + k];
    const float bc = b1[c];
    for (int r = 0; r < 32; ++r) {
      float a = bc;
      #pragma unroll
      for (int k = 0; k < 16; ++k) a = fmaf(zs[r][k], w[k], a);
      h1[(r0 + r) * 1024 + c] = f2b(tanhf(a));
    }
  }
}

// ---------------- K4a: g1f = tanh(f1) + f1*s1 ----------------
__global__ __launch_bounds__(256) void k4a(
    const float* __restrict__ z, const float* __restrict__ Wp,
    const float* __restrict__ bp, const float* __restrict__ Wf1,
    const float* __restrict__ bf1v, const bf16* __restrict__ s1,
    bf16* __restrict__ g1f, long grow0)
{
  __shared__ float zs[32][16];
  __shared__ float us[32][4];
  const int tid = threadIdx.x;
  const long r0 = (long)blockIdx.x * 32;
  for (int i = tid; i < 512; i += 256) {
    int r = i >> 4, c = i & 15;
    zs[r][c] = z[(grow0 + r0 + r) * 16 + c];
  }
  __syncthreads();
  if (tid < 128) {
    int r = tid >> 2, a = tid & 3;
    float acc = bp[a];
    #pragma unroll
    for (int k = 0; k < 16; ++k) acc = fmaf(zs[r][k], Wp[a * 16 + k], acc);
    us[r][a] = tanhf(acc);
  }
  __syncthreads();
  #pragma unroll
  for (int jj = 0; jj < 4; ++jj) {
    const int c = tid + jj * 256;
    float w[20];
    #pragma unroll
    for (int k = 0; k < 20; ++k) w[k] = Wf1[c * 20 + k];
    const float bc = bf1v[c];
    for (int r = 0; r < 32; ++r) {
      float f = bc;
      #pragma unroll
      for (int k = 0; k < 16; ++k) f = fmaf(zs[r][k], w[k], f);
      #pragma unroll
      for (int a = 0; a < 4; ++a) f = fmaf(us[r][a], w[16 + a], f);
      float sv = __bfloat162float(s1[(r0 + r) * 1024 + c]);
      g1f[(r0 + r) * 1024 + c] = f2b(tanhf(f) + f * sv);
    }
  }
}

// ---------------- MFMA GEMM: C = A[RxK=1024] * B, B given as Bp[n][k] -------
// EPI 0 (K2): h2=tanh(x+b2); O1=s1=1-h2^2; O2=gb=s1*Wh
// EPI 1 (K3): O1=g1b = x * s0,  s0 = 1-h1^2
// EPI 2 (K4b): f=x+bf2; O1=g2f = tanh(f)+f*s0
template<int EPI>
__global__ __launch_bounds__(256) void gemm_k(
    const bf16* __restrict__ A, const bf16* __restrict__ Bp,
    const float* __restrict__ bias, const float* __restrict__ Whv,
    const bf16* __restrict__ h1, bf16* __restrict__ O1, bf16* __restrict__ O2)
{
  __shared__ bf16 As[BM * BK];
  __shared__ bf16 Bs[BN * BK];
  const int tid = threadIdx.x;
  const int lane = tid & 63, wid = tid >> 6;
  const int wr = wid >> 1, wc = wid & 1;
  const int fr = lane & 15, kg = lane >> 4;
  const long row0 = (long)blockIdx.x * BM;
  const int col0 = blockIdx.y * BN;

  const int e0 = wid * 512 + lane * 8;     // staging element offset
  const int sr0 = e0 >> 5, sk0 = e0 & 31;  // row / k within tile

  f32x4 acc[4][4];
  #pragma unroll
  for (int m = 0; m < 4; ++m)
    #pragma unroll
    for (int n = 0; n < 4; ++n) acc[m][n] = (f32x4){0.f, 0.f, 0.f, 0.f};

  for (int kt = 0; kt < 1024 / BK; ++kt) {
    const int k0 = kt * BK;
    #pragma unroll
    for (int it = 0; it < 2; ++it) {
      const bf16* ga = A + (row0 + sr0 + it * 64) * 1024 + (k0 + sk0);
      GLOAD_LDS16(ga, As + it * 2048 + wid * 512 + lane * 8);
      const bf16* gbp = Bp + (long)(col0 + sr0 + it * 64) * 1024 + (k0 + sk0);
      GLOAD_LDS16(gbp, Bs + it * 2048 + wid * 512 + lane * 8);
    }
    __syncthreads();
    short8 af[4], bfr[4];
    #pragma unroll
    for (int m = 0; m < 4; ++m)
      af[m] = *(const short8*)(As + (wr * 64 + m * 16 + fr) * 32 + kg * 8);
    #pragma unroll
    for (int n = 0; n < 4; ++n)
      bfr[n] = *(const short8*)(Bs + (wc * 64 + n * 16 + fr) * 32 + kg * 8);
    #pragma unroll
    for (int m = 0; m < 4; ++m)
      #pragma unroll
      for (int n = 0; n < 4; ++n)
        acc[m][n] = __builtin_amdgcn_mfma_f32_16x16x32_bf16(af[m], bfr[n], acc[m][n], 0, 0, 0);
    __syncthreads();
  }

  #pragma unroll
  for (int m = 0; m < 4; ++m) {
    const long gr0 = row0 + wr * 64 + m * 16 + kg * 4;
    #pragma unroll
    for (int n = 0; n < 4; ++n) {
      const int gc = col0 + wc * 64 + n * 16 + fr;
      f32x4 v = acc[m][n];
      #pragma unroll
      for (int j = 0; j < 4; ++j) {
        const long idx = (gr0 + j) * 1024 + gc;
        float x = v[j];
        if (EPI == 0) {
          float h = tanhf(x + bias[gc]);
          float s1v = 1.f - h * h;
          O1[idx] = f2b(s1v);
          O2[idx] = f2b(s1v * Whv[gc]);
        } else if (EPI == 1) {
          float hh = __bfloat162float(h1[idx]);
          O1[idx] = f2b(x * (1.f - hh * hh));
        } else {
          float f = x + bias[gc];
          float hh = __bfloat162float(h1[idx]);
          O1[idx] = f2b(tanhf(f) + f * (1.f - hh * hh));
        }
      }
    }
  }
}

// ---------------- K6: dz+out projections, bias, symplectic permute ----------
// lane = (j:4b, half:1b, ig:1b); wave handles one row
__global__ __launch_bounds__(256) void k6(
    const bf16* __restrict__ g1b, const bf16* __restrict__ g2f,
    const bf16* __restrict__ Wc, const float* __restrict__ bff,
    float* __restrict__ out, long grow0)
{
  const int tid = threadIdx.x, lane = tid & 63, wid = tid >> 6;
  const long r = (long)blockIdx.x * 4 + wid;
  const int j = lane & 15, half = (lane >> 4) & 1, ig = lane >> 5;
  const int jp = half * 16 + j;
  const bf16* g = (half ? g2f : g1b) + r * 1024 + ig * 512;
  const unsigned short* W = (const unsigned short*)Wc;
  float acc = 0.f;
  for (int i = 0; i < 512; i += 8) {
    short8 gv = *(const short8*)(g + i);
    #pragma unroll
    for (int e = 0; e < 8; ++e)
      acc = fmaf(b2f((unsigned short)gv[e]), b2f(W[(ig * 512 + i + e) * 32 + jp]), acc);
  }
  acc += __shfl_xor(acc, 32);
  float s = acc + __shfl_xor(acc, 16);
  s += bff[j];
  float v = __shfl(s, (j + 8) & 15);
  if (lane < 16) out[(grow0 + r) * 16 + lane] = (lane < 8) ? v : -v;
}

// ---------------- host ----------------
extern "C" void kernel_launch(void* const* d_in, const int* in_sizes, int n_in,
                              void* d_out, int out_size, void* d_ws, size_t ws_size,
                              hipStream_t stream) {
  const float* z   = (const float*)d_in[1];
  const float* W1  = (const float*)d_in[2];
  const float* b1  = (const float*)d_in[3];
  const float* W2  = (const float*)d_in[4];
  const float* b2  = (const float*)d_in[5];
  const float* Wh  = (const float*)d_in[6];
  const float* Wf1 = (const float*)d_in[8];
  const float* bf1 = (const float*)d_in[9];
  const float* Wf2 = (const float*)d_in[10];
  const float* bf2 = (const float*)d_in[11];
  const float* Wff = (const float*)d_in[12];
  const float* bff = (const float*)d_in[13];
  const float* Wp  = (const float*)d_in[14];
  const float* bp  = (const float*)d_in[15];
  float* out = (float*)d_out;
  const int N = in_sizes[1] / 16;

  char* p = (char*)d_ws;
  auto alloc = [&](size_t bytes) {
    char* q = p; p += (bytes + 255) & ~(size_t)255; return q;
  };
  bf16* W2bf  = (bf16*)alloc(1024 * 1024 * 2);
  bf16* W2Tbf = (bf16*)alloc(1024 * 1024 * 2);
  bf16* Wf2bf = (bf16*)alloc(1024 * 1024 * 2);
  bf16* Wc    = (bf16*)alloc(1024 * 32 * 2);
  size_t wbytes = (size_t)(p - (char*)d_ws);

  int CK = N;  // chunk rows (power of two, divides N)
  while (CK > 128 && wbytes + 4ull * (size_t)CK * 2048ull > ws_size) CK >>= 1;
  bf16* actA = (bf16*)alloc((size_t)CK * 2048);  // h1
  bf16* actB = (bf16*)alloc((size_t)CK * 2048);  // s1 -> g1b
  bf16* actC = (bf16*)alloc((size_t)CK * 2048);  // gb -> g2f
  bf16* actD = (bf16*)alloc((size_t)CK * 2048);  // g1f

  prep<<<4096, 256, 0, stream>>>(W2, Wf2, W1, Wff, W2bf, W2Tbf, Wf2bf, Wc);

  for (long r0 = 0; r0 < N; r0 += CK) {
    k1<<<CK / 32, 256, 0, stream>>>(z, W1, b1, actA, r0);
    gemm_k<0><<<dim3(CK / 128, 8), 256, 0, stream>>>(actA, W2bf, b2, Wh, nullptr, actB, actC);
    k4a<<<CK / 32, 256, 0, stream>>>(z, Wp, bp, Wf1, bf1, actB, actD, r0);
    gemm_k<1><<<dim3(CK / 128, 8), 256, 0, stream>>>(actC, W2Tbf, nullptr, nullptr, actA, actB, nullptr);
    gemm_k<2><<<dim3(CK / 128, 8), 256, 0, stream>>>(actD, Wf2bf, bf2, nullptr, actA, actC, nullptr);
    k6<<<CK / 4, 256, 0, stream>>>(actB, actC, Wc, bff, out, r0);
  }
}

// Round 2
// 567.756 us; speedup vs baseline: 1.2736x; 1.2736x over previous
//
#include <hip/hip_runtime.h>
#include <hip/hip_bf16.h>

typedef __hip_bfloat16 bf16;
typedef __attribute__((ext_vector_type(8))) short short8;
typedef __attribute__((ext_vector_type(4))) float f32x4;

__device__ __forceinline__ float b2f(unsigned short u) {
  union { unsigned u; float f; } x; x.u = ((unsigned)u) << 16; return x.f;
}
__device__ __forceinline__ bf16 f2b(float f) { return __float2bfloat16(f); }

#define BM 128
#define BN 128
#define BK 32

#define GLOAD_LDS16(gp, lp) __builtin_amdgcn_global_load_lds( \
    (const __attribute__((address_space(1))) void*)(gp), \
    (__attribute__((address_space(3))) void*)(lp), 16, 0, 0)

// ---------------- prep: bf16 weight layouts ----------------
// W2bf[n][k]  = W2[n][k]   (B for K2)
// W2Tbf[n][k] = W2[k][n]   (B for K3)
// Wf2bf[n][k] = Wf2[n][k]  (B for K4b)
// W1n[j][k]   = W1[k][j]   (B for k6m, dH path)
// Wffn[j][k]  = Wff[j][k]  (B for k6m, flex path)
__global__ __launch_bounds__(256) void prep(
    const float* __restrict__ W2, const float* __restrict__ Wf2,
    const float* __restrict__ W1, const float* __restrict__ Wff,
    bf16* __restrict__ W2bf, bf16* __restrict__ W2Tbf,
    bf16* __restrict__ Wf2bf, bf16* __restrict__ W1n,
    bf16* __restrict__ Wffn)
{
  int i = blockIdx.x * 256 + threadIdx.x;
  int r = i >> 10, c = i & 1023;
  W2bf[i]  = f2b(W2[i]);
  W2Tbf[i] = f2b(W2[c * 1024 + r]);
  Wf2bf[i] = f2b(Wf2[i]);
  if (i < 16 * 1024) {
    W1n[i]  = f2b(W1[c * 16 + r]);
    Wffn[i] = f2b(Wff[i]);
  }
}

// ---------------- K1: h1 = tanh(z @ W1^T + b1) ----------------
__global__ __launch_bounds__(256) void k1(
    const float* __restrict__ z, const float* __restrict__ W1,
    const float* __restrict__ b1, bf16* __restrict__ h1, long grow0)
{
  __shared__ float zs[32][16];
  const int tid = threadIdx.x;
  const long r0 = (long)blockIdx.x * 32;
  for (int i = tid; i < 512; i += 256) {
    int r = i >> 4, c = i & 15;
    zs[r][c] = z[(grow0 + r0 + r) * 16 + c];
  }
  __syncthreads();
  #pragma unroll
  for (int jj = 0; jj < 4; ++jj) {
    const int c = tid + jj * 256;
    float w[16];
    #pragma unroll
    for (int k = 0; k < 16; ++k) w[k] = W1[c * 16 + k];
    const float bc = b1[c];
    for (int r = 0; r < 32; ++r) {
      float a = bc;
      #pragma unroll
      for (int k = 0; k < 16; ++k) a = fmaf(zs[r][k], w[k], a);
      h1[(r0 + r) * 1024 + c] = f2b(tanhf(a));
    }
  }
}

// ---------------- K4a: g1f = tanh(f1) + f1*s1 ----------------
__global__ __launch_bounds__(256) void k4a(
    const float* __restrict__ z, const float* __restrict__ Wp,
    const float* __restrict__ bp, const float* __restrict__ Wf1,
    const float* __restrict__ bf1v, const bf16* __restrict__ s1,
    bf16* __restrict__ g1f, long grow0)
{
  __shared__ float zs[32][16];
  __shared__ float us[32][4];
  const int tid = threadIdx.x;
  const long r0 = (long)blockIdx.x * 32;
  for (int i = tid; i < 512; i += 256) {
    int r = i >> 4, c = i & 15;
    zs[r][c] = z[(grow0 + r0 + r) * 16 + c];
  }
  __syncthreads();
  if (tid < 128) {
    int r = tid >> 2, a = tid & 3;
    float acc = bp[a];
    #pragma unroll
    for (int k = 0; k < 16; ++k) acc = fmaf(zs[r][k], Wp[a * 16 + k], acc);
    us[r][a] = tanhf(acc);
  }
  __syncthreads();
  #pragma unroll
  for (int jj = 0; jj < 4; ++jj) {
    const int c = tid + jj * 256;
    float w[20];
    #pragma unroll
    for (int k = 0; k < 20; ++k) w[k] = Wf1[c * 20 + k];
    const float bc = bf1v[c];
    for (int r = 0; r < 32; ++r) {
      float f = bc;
      #pragma unroll
      for (int k = 0; k < 16; ++k) f = fmaf(zs[r][k], w[k], f);
      #pragma unroll
      for (int a = 0; a < 4; ++a) f = fmaf(us[r][a], w[16 + a], f);
      float sv = __bfloat162float(s1[(r0 + r) * 1024 + c]);
      g1f[(r0 + r) * 1024 + c] = f2b(tanhf(f) + f * sv);
    }
  }
}

// ---------------- MFMA GEMM: C = A[RxK=1024] * B, B given as Bp[n][k] -------
// EPI 0 (K2): h2=tanh(x+b2); O1=s1=1-h2^2; O2=gb=s1*Wh
// EPI 1 (K3): O1=g1b = x * s0,  s0 = 1-h1^2
// EPI 2 (K4b): f=x+bf2; O1=g2f = tanh(f)+f*s0
template<int EPI>
__global__ __launch_bounds__(256) void gemm_k(
    const bf16* __restrict__ A, const bf16* __restrict__ Bp,
    const float* __restrict__ bias, const float* __restrict__ Whv,
    const bf16* __restrict__ h1, bf16* __restrict__ O1, bf16* __restrict__ O2)
{
  __shared__ bf16 As[BM * BK];
  __shared__ bf16 Bs[BN * BK];
  const int tid = threadIdx.x;
  const int lane = tid & 63, wid = tid >> 6;
  const int wr = wid >> 1, wc = wid & 1;
  const int fr = lane & 15, kg = lane >> 4;
  const long row0 = (long)blockIdx.x * BM;
  const int col0 = blockIdx.y * BN;

  const int e0 = wid * 512 + lane * 8;     // staging element offset
  const int sr0 = e0 >> 5, sk0 = e0 & 31;  // row / k within tile

  f32x4 acc[4][4];
  #pragma unroll
  for (int m = 0; m < 4; ++m)
    #pragma unroll
    for (int n = 0; n < 4; ++n) acc[m][n] = (f32x4){0.f, 0.f, 0.f, 0.f};

  for (int kt = 0; kt < 1024 / BK; ++kt) {
    const int k0 = kt * BK;
    #pragma unroll
    for (int it = 0; it < 2; ++it) {
      const bf16* ga = A + (row0 + sr0 + it * 64) * 1024 + (k0 + sk0);
      GLOAD_LDS16(ga, As + it * 2048 + wid * 512 + lane * 8);
      const bf16* gbp = Bp + (long)(col0 + sr0 + it * 64) * 1024 + (k0 + sk0);
      GLOAD_LDS16(gbp, Bs + it * 2048 + wid * 512 + lane * 8);
    }
    __syncthreads();
    short8 af[4], bfr[4];
    #pragma unroll
    for (int m = 0; m < 4; ++m)
      af[m] = *(const short8*)(As + (wr * 64 + m * 16 + fr) * 32 + kg * 8);
    #pragma unroll
    for (int n = 0; n < 4; ++n)
      bfr[n] = *(const short8*)(Bs + (wc * 64 + n * 16 + fr) * 32 + kg * 8);
    #pragma unroll
    for (int m = 0; m < 4; ++m)
      #pragma unroll
      for (int n = 0; n < 4; ++n)
        acc[m][n] = __builtin_amdgcn_mfma_f32_16x16x32_bf16(af[m], bfr[n], acc[m][n], 0, 0, 0);
    __syncthreads();
  }

  #pragma unroll
  for (int m = 0; m < 4; ++m) {
    const long gr0 = row0 + wr * 64 + m * 16 + kg * 4;
    #pragma unroll
    for (int n = 0; n < 4; ++n) {
      const int gc = col0 + wc * 64 + n * 16 + fr;
      f32x4 v = acc[m][n];
      #pragma unroll
      for (int j = 0; j < 4; ++j) {
        const long idx = (gr0 + j) * 1024 + gc;
        float x = v[j];
        if (EPI == 0) {
          float h = tanhf(x + bias[gc]);
          float s1v = 1.f - h * h;
          O1[idx] = f2b(s1v);
          O2[idx] = f2b(s1v * Whv[gc]);
        } else if (EPI == 1) {
          float hh = __bfloat162float(h1[idx]);
          O1[idx] = f2b(x * (1.f - hh * hh));
        } else {
          float f = x + bias[gc];
          float hh = __bfloat162float(h1[idx]);
          O1[idx] = f2b(tanhf(f) + f * (1.f - hh * hh));
        }
      }
    }
  }
}

// ---------------- k6m: P[y] = G_y @ Wn_y^T  (MFMA, N-dim=16) ----------------
// y=0: G=g1b, Wn=W1n ; y=1: G=g2f, Wn=Wffn. Each wave: 16 rows, K=1024 loop.
__global__ __launch_bounds__(128) void k6m(
    const bf16* __restrict__ g1b, const bf16* __restrict__ g2f,
    const bf16* __restrict__ W1n, const bf16* __restrict__ Wffn,
    float* __restrict__ Pb, int ck)
{
  const int lane = threadIdx.x & 63, wid = threadIdx.x >> 6;
  const int fr = lane & 15, kg = lane >> 4;
  const int y = blockIdx.y;
  const bf16* __restrict__ G  = y ? g2f : g1b;
  const bf16* __restrict__ Wn = y ? Wffn : W1n;
  float* __restrict__ P = Pb + (size_t)y * ck * 16;
  const long r0 = (long)blockIdx.x * 32 + wid * 16;

  f32x4 acc = (f32x4){0.f, 0.f, 0.f, 0.f};
  const bf16* ga = G + (r0 + fr) * 1024 + kg * 8;
  const bf16* gw = Wn + fr * 1024 + kg * 8;
  #pragma unroll 4
  for (int kt = 0; kt < 32; ++kt) {
    short8 a = *(const short8*)(ga + kt * 32);
    short8 b = *(const short8*)(gw + kt * 32);
    acc = __builtin_amdgcn_mfma_f32_16x16x32_bf16(a, b, acc, 0, 0, 0);
  }
  #pragma unroll
  for (int j = 0; j < 4; ++j)
    P[(r0 + kg * 4 + j) * 16 + fr] = acc[j];
}

// ---------------- k7: out = J*(P0 + P1 + bff) with symplectic permute ------
__global__ __launch_bounds__(256) void k7(
    const float* __restrict__ Pb, const float* __restrict__ bff,
    float* __restrict__ out, long grow0, int ck)
{
  int i = blockIdx.x * 256 + threadIdx.x;
  if (i >= ck * 16) return;
  int r = i >> 4, j = i & 15;
  int jp = (j + 8) & 15;
  float s = Pb[r * 16 + jp] + Pb[(size_t)ck * 16 + r * 16 + jp] + bff[jp];
  out[(grow0 + r) * 16 + j] = (j < 8) ? s : -s;
}

// ---------------- host ----------------
extern "C" void kernel_launch(void* const* d_in, const int* in_sizes, int n_in,
                              void* d_out, int out_size, void* d_ws, size_t ws_size,
                              hipStream_t stream) {
  const float* z   = (const float*)d_in[1];
  const float* W1  = (const float*)d_in[2];
  const float* b1  = (const float*)d_in[3];
  const float* W2  = (const float*)d_in[4];
  const float* b2  = (const float*)d_in[5];
  const float* Wh  = (const float*)d_in[6];
  const float* Wf1 = (const float*)d_in[8];
  const float* bf1 = (const float*)d_in[9];
  const float* Wf2 = (const float*)d_in[10];
  const float* bf2 = (const float*)d_in[11];
  const float* Wff = (const float*)d_in[12];
  const float* bff = (const float*)d_in[13];
  const float* Wp  = (const float*)d_in[14];
  const float* bp  = (const float*)d_in[15];
  float* out = (float*)d_out;
  const int N = in_sizes[1] / 16;

  char* p = (char*)d_ws;
  auto alloc = [&](size_t bytes) {
    char* q = p; p += (bytes + 255) & ~(size_t)255; return q;
  };
  bf16* W2bf  = (bf16*)alloc(1024 * 1024 * 2);
  bf16* W2Tbf = (bf16*)alloc(1024 * 1024 * 2);
  bf16* Wf2bf = (bf16*)alloc(1024 * 1024 * 2);
  bf16* W1n   = (bf16*)alloc(16 * 1024 * 2);
  bf16* Wffn  = (bf16*)alloc(16 * 1024 * 2);
  size_t wbytes = (size_t)(p - (char*)d_ws);

  int CK = N;  // chunk rows (power of two, divides N)
  while (CK > 128 &&
         wbytes + (size_t)CK * (4 * 2048 + 2 * 16 * 4) + 4096 > ws_size)
    CK >>= 1;
  bf16* actA = (bf16*)alloc((size_t)CK * 2048);   // h1
  bf16* actB = (bf16*)alloc((size_t)CK * 2048);   // s1 -> g1b
  bf16* actC = (bf16*)alloc((size_t)CK * 2048);   // gb -> g2f
  bf16* actD = (bf16*)alloc((size_t)CK * 2048);   // g1f
  float* Pb  = (float*)alloc((size_t)CK * 2 * 16 * 4);  // k6m partials

  prep<<<4096, 256, 0, stream>>>(W2, Wf2, W1, Wff, W2bf, W2Tbf, Wf2bf, W1n, Wffn);

  for (long r0 = 0; r0 < N; r0 += CK) {
    k1<<<CK / 32, 256, 0, stream>>>(z, W1, b1, actA, r0);
    gemm_k<0><<<dim3(CK / 128, 8), 256, 0, stream>>>(actA, W2bf, b2, Wh, nullptr, actB, actC);
    k4a<<<CK / 32, 256, 0, stream>>>(z, Wp, bp, Wf1, bf1, actB, actD, r0);
    gemm_k<1><<<dim3(CK / 128, 8), 256, 0, stream>>>(actC, W2Tbf, nullptr, nullptr, actA, actB, nullptr);
    gemm_k<2><<<dim3(CK / 128, 8), 256, 0, stream>>>(actD, Wf2bf, bf2, nullptr, actA, actC, nullptr);
    k6m<<<dim3(CK / 32, 2), 128, 0, stream>>>(actB, actC, W1n, Wffn, Pb, CK);
    k7<<<(CK * 16 + 255) / 256, 256, 0, stream>>>(Pb, bff, out, r0, CK);
  }
}

// Round 4
// 451.179 us; speedup vs baseline: 1.6027x; 1.2584x over previous
//
#include <hip/hip_runtime.h>
#include <hip/hip_bf16.h>

typedef __hip_bfloat16 bf16;
typedef __attribute__((ext_vector_type(8))) short short8;
typedef __attribute__((ext_vector_type(4))) short s16x4;
typedef __attribute__((ext_vector_type(4))) float f32x4;

__device__ __forceinline__ bf16 f2b(float f) { return __float2bfloat16(f); }
__device__ __forceinline__ short bfbits(float f) {
  union { float f; unsigned u; } x; x.f = f;
  unsigned r = x.u + 0x7fff + ((x.u >> 16) & 1);  // RNE
  return (short)(r >> 16);
}
// tanh(x) = sign(x) * (1-t)/(1+t), t = e^{-2|x|}  — ~8 VALU ops, err ~1e-6
__device__ __forceinline__ float tanh_fast(float x) {
  float t = __expf(-2.f * fabsf(x));
  float r = (1.f - t) * __builtin_amdgcn_rcpf(1.f + t);
  return copysignf(r, x);
}

#define BM 128
#define BN 128
#define BK 32

#define GLOAD_LDS16(gp, lp) __builtin_amdgcn_global_load_lds( \
    (const __attribute__((address_space(1))) void*)(gp), \
    (__attribute__((address_space(3))) void*)(lp), 16, 0, 0)

// ---------------- prep: bf16 weight layouts (coalesced transpose) ----------
// W2bf[n][k]  = W2[n][k]   (B for K2)
// W2Tbf[n][k] = W2[k][n]   (B for K3)
// Wf2bf[n][k] = Wf2[n][k]  (B for K4b)
// W1n[j][k]   = W1[k][j]   (B for k6f, dH path)
// Wffn[j][k]  = Wff[j][k]  (B for k6f, flex path)
__global__ __launch_bounds__(256) void prep(
    const float* __restrict__ W2, const float* __restrict__ Wf2,
    const float* __restrict__ W1, const float* __restrict__ Wff,
    bf16* __restrict__ W2bf, bf16* __restrict__ W2Tbf,
    bf16* __restrict__ Wf2bf, bf16* __restrict__ W1n,
    bf16* __restrict__ Wffn)
{
  __shared__ float T[32][33];
  const int tid = threadIdx.x, bx = blockIdx.x;
  const int tx = bx & 31, ty = bx >> 5;          // tile col / row (32x32 tiles)
  const int r = tid >> 3, c4 = (tid & 7) * 4;
  const long ibase = (long)(ty * 32 + r) * 1024 + tx * 32 + c4;

  f32x4 v = *(const f32x4*)(W2 + ibase);
  f32x4 vf = *(const f32x4*)(Wf2 + ibase);
  s16x4 sv, sf;
  #pragma unroll
  for (int j = 0; j < 4; ++j) {
    sv[j] = bfbits(v[j]); sf[j] = bfbits(vf[j]);
    T[r][c4 + j] = v[j];
  }
  *(s16x4*)(W2bf + ibase) = sv;
  *(s16x4*)(Wf2bf + ibase) = sf;
  __syncthreads();
  const int oc = tid >> 3, or4 = (tid & 7) * 4;
  s16x4 st;
  #pragma unroll
  for (int j = 0; j < 4; ++j) st[j] = bfbits(T[or4 + j][oc]);
  *(s16x4*)(W2Tbf + (long)(tx * 32 + oc) * 1024 + ty * 32 + or4) = st;

  if (bx < 32) {  // W1n (16x1024, transpose of W1) + Wffn (straight)
    #pragma unroll
    for (int rep = 0; rep < 2; ++rep) {
      int i = bx * 512 + rep * 256 + tid;
      int rr = i >> 10, cc = i & 1023;
      W1n[i] = f2b(W1[cc * 16 + rr]);
      Wffn[i] = f2b(Wff[i]);
    }
  }
}

// ---------------- K1: h1 = tanh(z @ W1^T + b1) ----------------
__global__ __launch_bounds__(256) void k1(
    const float* __restrict__ z, const float* __restrict__ W1,
    const float* __restrict__ b1, bf16* __restrict__ h1, long grow0)
{
  __shared__ float zs[32][16];
  const int tid = threadIdx.x;
  const long r0 = (long)blockIdx.x * 32;
  for (int i = tid; i < 512; i += 256) {
    int r = i >> 4, c = i & 15;
    zs[r][c] = z[(grow0 + r0 + r) * 16 + c];
  }
  __syncthreads();
  #pragma unroll
  for (int jj = 0; jj < 4; ++jj) {
    const int c = tid + jj * 256;
    float w[16];
    #pragma unroll
    for (int k = 0; k < 16; ++k) w[k] = W1[c * 16 + k];
    const float bc = b1[c];
    for (int r = 0; r < 32; ++r) {
      float a = bc;
      #pragma unroll
      for (int k = 0; k < 16; ++k) a = fmaf(zs[r][k], w[k], a);
      h1[(r0 + r) * 1024 + c] = f2b(tanh_fast(a));
    }
  }
}

// ---------------- K4a: g1f = tanh(f1) + f1*s1 ----------------
__global__ __launch_bounds__(256) void k4a(
    const float* __restrict__ z, const float* __restrict__ Wp,
    const float* __restrict__ bp, const float* __restrict__ Wf1,
    const float* __restrict__ bf1v, const bf16* __restrict__ s1,
    bf16* __restrict__ g1f, long grow0)
{
  __shared__ float zs[32][16];
  __shared__ float us[32][4];
  const int tid = threadIdx.x;
  const long r0 = (long)blockIdx.x * 32;
  for (int i = tid; i < 512; i += 256) {
    int r = i >> 4, c = i & 15;
    zs[r][c] = z[(grow0 + r0 + r) * 16 + c];
  }
  __syncthreads();
  if (tid < 128) {
    int r = tid >> 2, a = tid & 3;
    float acc = bp[a];
    #pragma unroll
    for (int k = 0; k < 16; ++k) acc = fmaf(zs[r][k], Wp[a * 16 + k], acc);
    us[r][a] = tanh_fast(acc);
  }
  __syncthreads();
  #pragma unroll
  for (int jj = 0; jj < 4; ++jj) {
    const int c = tid + jj * 256;
    float w[20];
    #pragma unroll
    for (int k = 0; k < 20; ++k) w[k] = Wf1[c * 20 + k];
    const float bc = bf1v[c];
    for (int r = 0; r < 32; ++r) {
      float f = bc;
      #pragma unroll
      for (int k = 0; k < 16; ++k) f = fmaf(zs[r][k], w[k], f);
      #pragma unroll
      for (int a = 0; a < 4; ++a) f = fmaf(us[r][a], w[16 + a], f);
      float sv = __bfloat162float(s1[(r0 + r) * 1024 + c]);
      g1f[(r0 + r) * 1024 + c] = f2b(tanh_fast(f) + f * sv);
    }
  }
}

// ---------------- MFMA GEMM: C = A[RxK=1024] * B, B given as Bp[n][k] -------
// LDS layout swizzled (T2, both-sides): slot (row, cc) holds k-chunk
// cc ^ ((row>>1)&3); staging pre-swizzles the GLOBAL source (rule 21).
// EPI 0 (K2): h2=tanh(x+b2); O1=s1=1-h2^2; O2=gb=s1*Wh
// EPI 1 (K3): O1=g1b = x * s0,  s0 = 1-h1^2
// EPI 2 (K4b): f=x+bf2; O1=g2f = tanh(f)+f*s0
template<int EPI>
__global__ __launch_bounds__(256) void gemm_k(
    const bf16* __restrict__ A, const bf16* __restrict__ Bp,
    const float* __restrict__ bias, const float* __restrict__ Whv,
    const bf16* __restrict__ h1, bf16* __restrict__ O1, bf16* __restrict__ O2)
{
  __shared__ bf16 As[BM * BK];
  __shared__ bf16 Bs[BN * BK];
  const int tid = threadIdx.x;
  const int lane = tid & 63, wid = tid >> 6;
  const int wr = wid >> 1, wc = wid & 1;
  const int fr = lane & 15, kg = lane >> 4;
  const long row0 = (long)blockIdx.x * BM;
  const int col0 = blockIdx.y * BN;

  const int sr0 = tid >> 2;                            // staging row in tile
  const int sk0 = ((tid & 3) ^ ((tid >> 3) & 3)) * 8;  // pre-swizzled k-chunk
  const int swr = (fr >> 1) & 3;                       // read-side XOR term

  f32x4 acc[4][4];
  #pragma unroll
  for (int m = 0; m < 4; ++m)
    #pragma unroll
    for (int n = 0; n < 4; ++n) acc[m][n] = (f32x4){0.f, 0.f, 0.f, 0.f};

  for (int kt = 0; kt < 1024 / BK; ++kt) {
    const int k0 = kt * BK;
    #pragma unroll
    for (int it = 0; it < 2; ++it) {
      const bf16* ga = A + (row0 + sr0 + it * 64) * 1024 + (k0 + sk0);
      GLOAD_LDS16(ga, As + it * 2048 + tid * 8);
      const bf16* gbp = Bp + (long)(col0 + sr0 + it * 64) * 1024 + (k0 + sk0);
      GLOAD_LDS16(gbp, Bs + it * 2048 + tid * 8);
    }
    __syncthreads();
    short8 af[4], bfr[4];
    #pragma unroll
    for (int m = 0; m < 4; ++m)
      af[m] = *(const short8*)(As + (wr * 64 + m * 16 + fr) * 32 + (kg ^ swr) * 8);
    #pragma unroll
    for (int n = 0; n < 4; ++n)
      bfr[n] = *(const short8*)(Bs + (wc * 64 + n * 16 + fr) * 32 + (kg ^ swr) * 8);
    #pragma unroll
    for (int m = 0; m < 4; ++m)
      #pragma unroll
      for (int n = 0; n < 4; ++n)
        acc[m][n] = __builtin_amdgcn_mfma_f32_16x16x32_bf16(af[m], bfr[n], acc[m][n], 0, 0, 0);
    __syncthreads();
  }

  #pragma unroll
  for (int m = 0; m < 4; ++m) {
    const long gr0 = row0 + wr * 64 + m * 16 + kg * 4;
    #pragma unroll
    for (int n = 0; n < 4; ++n) {
      const int gc = col0 + wc * 64 + n * 16 + fr;
      f32x4 v = acc[m][n];
      #pragma unroll
      for (int j = 0; j < 4; ++j) {
        const long idx = (gr0 + j) * 1024 + gc;
        float x = v[j];
        if (EPI == 0) {
          float h = tanh_fast(x + bias[gc]);
          float s1v = 1.f - h * h;
          O1[idx] = f2b(s1v);
          O2[idx] = f2b(s1v * Whv[gc]);
        } else if (EPI == 1) {
          float hh = __bfloat162float(h1[idx]);
          O1[idx] = f2b(x * (1.f - hh * hh));
        } else {
          float f = x + bias[gc];
          float hh = __bfloat162float(h1[idx]);
          O1[idx] = f2b(tanh_fast(f) + f * (1.f - hh * hh));
        }
      }
    }
  }
}

// ---------------- k6f: out = J*(g1b@W1 + g2f@Wff^T + bff) ------------------
// 4 waves / 32 rows: wave = (y:1b, half:1b); partials combined in LDS.
__global__ __launch_bounds__(256) void k6f(
    const bf16* __restrict__ g1b, const bf16* __restrict__ g2f,
    const bf16* __restrict__ W1n, const bf16* __restrict__ Wffn,
    const float* __restrict__ bff, float* __restrict__ out, long grow0)
{
  __shared__ float P[2][32][16];
  const int tid = threadIdx.x, lane = tid & 63, wid = tid >> 6;
  const int fr = lane & 15, kg = lane >> 4;
  const int y = wid >> 1, half = wid & 1;
  const long rb = (long)blockIdx.x * 32;
  const long r0 = rb + half * 16;
  const bf16* __restrict__ G  = y ? g2f : g1b;
  const bf16* __restrict__ Wn = y ? Wffn : W1n;

  f32x4 acc = (f32x4){0.f, 0.f, 0.f, 0.f};
  const bf16* ga = G + (r0 + fr) * 1024 + kg * 8;
  const bf16* gw = Wn + fr * 1024 + kg * 8;
  #pragma unroll 4
  for (int kt = 0; kt < 32; ++kt) {
    short8 a = *(const short8*)(ga + kt * 32);
    short8 b = *(const short8*)(gw + kt * 32);
    acc = __builtin_amdgcn_mfma_f32_16x16x32_bf16(a, b, acc, 0, 0, 0);
  }
  #pragma unroll
  for (int j = 0; j < 4; ++j) P[y][half * 16 + kg * 4 + j][fr] = acc[j];
  __syncthreads();
  #pragma unroll
  for (int e = tid; e < 512; e += 256) {
    int r = e >> 4, j = e & 15, jp = (j + 8) & 15;
    float s = P[0][r][jp] + P[1][r][jp] + bff[jp];
    out[(grow0 + rb + r) * 16 + j] = (j < 8) ? s : -s;
  }
}

// ---------------- host ----------------
extern "C" void kernel_launch(void* const* d_in, const int* in_sizes, int n_in,
                              void* d_out, int out_size, void* d_ws, size_t ws_size,
                              hipStream_t stream) {
  const float* z   = (const float*)d_in[1];
  const float* W1  = (const float*)d_in[2];
  const float* b1  = (const float*)d_in[3];
  const float* W2  = (const float*)d_in[4];
  const float* b2  = (const float*)d_in[5];
  const float* Wh  = (const float*)d_in[6];
  const float* Wf1 = (const float*)d_in[8];
  const float* bf1 = (const float*)d_in[9];
  const float* Wf2 = (const float*)d_in[10];
  const float* bf2 = (const float*)d_in[11];
  const float* Wff = (const float*)d_in[12];
  const float* bff = (const float*)d_in[13];
  const float* Wp  = (const float*)d_in[14];
  const float* bp  = (const float*)d_in[15];
  float* out = (float*)d_out;
  const int N = in_sizes[1] / 16;

  char* p = (char*)d_ws;
  auto alloc = [&](size_t bytes) {
    char* q = p; p += (bytes + 255) & ~(size_t)255; return q;
  };
  bf16* W2bf  = (bf16*)alloc(1024 * 1024 * 2);
  bf16* W2Tbf = (bf16*)alloc(1024 * 1024 * 2);
  bf16* Wf2bf = (bf16*)alloc(1024 * 1024 * 2);
  bf16* W1n   = (bf16*)alloc(16 * 1024 * 2);
  bf16* Wffn  = (bf16*)alloc(16 * 1024 * 2);
  size_t wbytes = (size_t)(p - (char*)d_ws);

  int CK = N;  // chunk rows (power of two, divides N)
  while (CK > 128 && wbytes + (size_t)CK * 4 * 2048 > ws_size) CK >>= 1;
  bf16* actA = (bf16*)alloc((size_t)CK * 2048);   // h1
  bf16* actB = (bf16*)alloc((size_t)CK * 2048);   // s1 -> g1b
  bf16* actC = (bf16*)alloc((size_t)CK * 2048);   // gb -> g2f
  bf16* actD = (bf16*)alloc((size_t)CK * 2048);   // g1f

  prep<<<1024, 256, 0, stream>>>(W2, Wf2, W1, Wff, W2bf, W2Tbf, Wf2bf, W1n, Wffn);

  for (long r0 = 0; r0 < N; r0 += CK) {
    k1<<<CK / 32, 256, 0, stream>>>(z, W1, b1, actA, r0);
    gemm_k<0><<<dim3(CK / 128, 8), 256, 0, stream>>>(actA, W2bf, b2, Wh, nullptr, actB, actC);
    k4a<<<CK / 32, 256, 0, stream>>>(z, Wp, bp, Wf1, bf1, actB, actD, r0);
    gemm_k<1><<<dim3(CK / 128, 8), 256, 0, stream>>>(actC, W2Tbf, nullptr, nullptr, actA, actB, nullptr);
    gemm_k<2><<<dim3(CK / 128, 8), 256, 0, stream>>>(actD, Wf2bf, bf2, nullptr, actA, actC, nullptr);
    k6f<<<CK / 32, 256, 0, stream>>>(actB, actC, W1n, Wffn, bff, out, r0);
  }
}